// Round 5
// baseline (255.497 us; speedup 1.0000x reference)
//
#include <hip/hip_runtime.h>
#include <hip/hip_bf16.h>
#include <math.h>

namespace {
constexpr int B_  = 8;
constexpr int U_  = 16384;
constexpr int S_  = 4096;
constexpr int E_  = 128;
constexpr int NTOK  = B_ * U_;   // 131072
constexpr int NCELL = B_ * S_;   // 32768
constexpr int CAP = 32;          // max off-grid tokens per cell (Poisson λ~4.1)
constexpr int SWZ2 = 2 * 16384;  // Wv,Wo swizzle elements
constexpr int ASZ  = 128 * 1024; // A fold: 128 k x 1024 n entries
}

typedef __attribute__((ext_vector_type(8))) short bf16x8;
typedef __attribute__((ext_vector_type(4))) float f32x4;

__device__ inline unsigned short bf16rne(float x) {
  unsigned u = __float_as_uint(x);
  u = u + 0x7fffu + ((u >> 16) & 1u);
  return (unsigned short)(u >> 16);
}

__device__ inline float bf16tof(unsigned short h) {
  return __uint_as_float(((unsigned)h) << 16);
}

__device__ inline bf16x8 pack8(float4 a, float4 b) {
  union { __hip_bfloat162 h; unsigned int u; } q0, q1, q2, q3;
  q0.h = __float22bfloat162_rn(make_float2(a.x, a.y));
  q1.h = __float22bfloat162_rn(make_float2(a.z, a.w));
  q2.h = __float22bfloat162_rn(make_float2(b.x, b.y));
  q3.h = __float22bfloat162_rn(make_float2(b.z, b.w));
  union { unsigned int u[4]; bf16x8 v; } r;
  r.u[0] = q0.u; r.u[1] = q1.u; r.u[2] = q2.u; r.u[3] = q3.u;
  return r.v;
}

// ------------------------------------------------------------------
// L1 setup (256 blocks x 1024):
//  blocks 0..15 : A-fold (QKt = latents @ A with A = 0.25*Wq·Wk^T folded,
//                 hi+lo bf16 planes in B-frag layout).
//  blocks 16..255: swizzle Wv/Wo -> bf16 B-frag; bucketize + CAP-scatter.
// ------------------------------------------------------------------
__global__ __launch_bounds__(1024, 4) void setup_kernel(
    const float* __restrict__ Wq, const float* __restrict__ Wk,
    const float* __restrict__ Wv, const float* __restrict__ Wo,
    const float* __restrict__ xc_off,
    unsigned short* __restrict__ Wsw,
    unsigned short* __restrict__ Ahi, unsigned short* __restrict__ Alo,
    int* __restrict__ cnt, int* __restrict__ sorted) {
  const int tid = threadIdx.x;

  if (blockIdx.x < 16) {
    const int n = tid;                       // 0..1023
    const int eg = n >> 6, h = (n >> 3) & 7, el = n & 7;
    const int e = eg * 8 + el;
    const float* wk = Wk + (size_t)e * 128 + h * 16;
    float wkv[16];
#pragma unroll
    for (int j = 0; j < 16; j += 4) {
      float4 t = *(const float4*)(wk + j);
      wkv[j] = t.x; wkv[j + 1] = t.y; wkv[j + 2] = t.z; wkv[j + 3] = t.w;
    }
    union { unsigned short s[8]; uint4 v; } rh, rl;
#pragma unroll
    for (int r = 0; r < 8; ++r) {
      const int k = (blockIdx.x << 3) + r;
      const float* wq = Wq + (size_t)k * 128 + h * 16;
      float acc = 0.f;
#pragma unroll
      for (int j = 0; j < 16; j += 4) {
        float4 t = *(const float4*)(wq + j);
        acc = fmaf(t.x, wkv[j], acc);
        acc = fmaf(t.y, wkv[j + 1], acc);
        acc = fmaf(t.z, wkv[j + 2], acc);
        acc = fmaf(t.w, wkv[j + 3], acc);
      }
      acc *= 0.25f;
      const unsigned short hh = bf16rne(acc);
      rh.s[r] = hh;
      rl.s[r] = bf16rne(acc - bf16tof(hh));
    }
    const size_t fo = ((size_t)blockIdx.x * 1024 + n) * 8;
    *(uint4*)(Ahi + fo) = rh.v;
    *(uint4*)(Alo + fo) = rl.v;
  } else {
    const int base = (blockIdx.x - 16) * 1024 + tid;
    const int stride = 240 * 1024;
    for (int i = base; i < SWZ2 + NTOK; i += stride) {
      if (i < SWZ2) {
        const int w = i >> 14, e = i & 16383;
        const int k = e >> 7, n = e & 127;
        const float* src = (w == 0) ? Wv : Wo;
        Wsw[w * 16384 + (((k >> 3) * 128 + n) << 3) + (k & 7)] = bf16rne(src[e]);
      } else {
        const int tok = i - SWZ2;
        const int b = tok >> 14;
        // EXACT replication of reference fp32 bucketize math
        const float sp = 1.0f / 63.0f;
        const float half = sp * 0.5f;
        const float x0 = xc_off[(size_t)tok * 2 + 0];
        const float x1 = xc_off[(size_t)tok * 2 + 1];
        float n0 = floorf((x0 - 0.0f + half) / sp);
        float n1 = floorf((x1 - 0.0f + half) / sp);
        n0 = fminf(fmaxf(n0, 0.0f), 63.0f);
        n1 = fminf(fmaxf(n1, 0.0f), 63.0f);
        const int seg = b * S_ + (int)(n0 * 64.0f + n1);
        const int rank = atomicAdd(&cnt[seg], 1);
        if (rank < CAP) sorted[seg * CAP + rank] = tok;
      }
    }
  }
}

// ------------------------------------------------------------------
// L1b: QKt = latents (4096x128) @ (Ahi+Alo) (128x1024), bf16 out in the
// swizzled per-cell layout. 256 blocks x 512 thr. No LDS.
// ------------------------------------------------------------------
__global__ __launch_bounds__(512, 4) void qkt_gemm(
    const float* __restrict__ latents,
    const unsigned short* __restrict__ Ahi,
    const unsigned short* __restrict__ Alo,
    unsigned short* __restrict__ QKt) {
  const int tid = threadIdx.x;
  const int wave = tid >> 6, lane = tid & 63;
  const int c = lane & 15, g = lane >> 4;
  const int rb = blockIdx.x >> 1, cb = blockIdx.x & 1;
  const int wr = wave >> 2, wc = wave & 3;
  const int t0 = rb * 32 + wr * 16;
  const int n0 = cb * 512 + wc * 128;

  f32x4 acc[8];
#pragma unroll
  for (int i = 0; i < 8; ++i) acc[i] = {0.f, 0.f, 0.f, 0.f};

  const float* arow = latents + (size_t)(t0 + c) * E_ + g * 8;
#pragma unroll
  for (int ks = 0; ks < 4; ++ks) {
    float4 a0 = *(const float4*)(arow + ks * 32);
    float4 a1 = *(const float4*)(arow + ks * 32 + 4);
    bf16x8 af = pack8(a0, a1);
    const size_t kg = (size_t)(ks * 4 + g) * 1024;
#pragma unroll
    for (int nt = 0; nt < 8; ++nt) {
      const size_t fo = (kg + n0 + nt * 16 + c) * 8;
      acc[nt] = __builtin_amdgcn_mfma_f32_16x16x32_bf16(
          af, *(const bf16x8*)(Ahi + fo), acc[nt], 0, 0, 0);
      acc[nt] = __builtin_amdgcn_mfma_f32_16x16x32_bf16(
          af, *(const bf16x8*)(Alo + fo), acc[nt], 0, 0, 0);
    }
  }
#pragma unroll
  for (int nt = 0; nt < 8; ++nt)
#pragma unroll
    for (int r = 0; r < 4; ++r)
      QKt[(size_t)(t0 + g * 4 + r) * 1024 + n0 + nt * 16 + c] = bf16rne(acc[nt][r]);
}

// ------------------------------------------------------------------
// L2: fused per-cell kernel. 4096 blocks x 256 thr (4 waves = 4 slots =
// 8 cells per block). Changes vs prev round:
//  - NO Wv/Wo LDS staging: B-frags read from global (32 KB, L1/L2-hot).
//    Removes block-start staging+barrier; LDS -> 11.5 KB -> 8 blocks/CU.
//  - On-grid token moved to FIXED slot 7 of chunk 0 (softmax is
//    permutation-invariant): chunk-0 addresses no longer depend on cnt.
//    sorted[] is pre-zeroed so speculative loads are safe; cnt (one int2
//    load, issued concurrently with sorted) joins only at the exp mask.
//  - do/while main loop so chunk 0 issues before `chunks` resolves.
//  - Single epilogue barrier (obuf is its own buffer now).
// Slot layout: chunk0 = off-tokens 0..6 + on-grid at slot 7; chunk k>=1
// = off-tokens 7+8(k-1) .. 14+8(k-1). chunks = 1 + (max(nA,nB)>>3).
// ------------------------------------------------------------------
__global__ __launch_bounds__(256, 8) void fused_cells(
    const float* __restrict__ zc_off, const float* __restrict__ zc_on,
    const float* __restrict__ fake, const int* __restrict__ ignore_flag,
    const unsigned short* __restrict__ Wv_sw,
    const unsigned short* __restrict__ Wo_sw,
    const unsigned short* __restrict__ QKt, const int* __restrict__ cnt,
    const int* __restrict__ sorted, float* __restrict__ out) {
  __shared__ __align__(16) float wbuf[4][8][24];  // [wave][head][t 0..15 +pad]
  __shared__ __align__(16) float obuf[16 * 132];  // finalize tile (rows 8-15 zero)
  const int tid = threadIdx.x;
  // zero garbage rows 8..15 once (read by finalize MFMA, rows discarded)
  for (int i = 8 * 132 + tid; i < 16 * 132; i += 256) obuf[i] = 0.f;
  const int ign = *ignore_flag;

  const int wave = tid >> 6, lane = tid & 63;
  const int c = lane & 15, g = lane >> 4;
  const int half = c >> 3;   // col-half: 0 -> cell A heads, 1 -> cell B heads
  const int hwr  = g >> 1;   // row-half this lane's C rows belong to
  const bf16x8* bv = (const bf16x8*)Wv_sw;

  const int slot = blockIdx.x * 4 + wave;
  const int cA = slot * 2, cB = cA + 1;
  const int sA = cA & (S_ - 1);            // cA even => sA even, sB = sA+1
  const int2 cc = *(const int2*)(cnt + cA);  // one 8B load: {cnt[cA], cnt[cB]}
  const int nA = min(cc.x, CAP);
  const int nB = min(cc.y, CAP);
  const int cH = half ? cB : cA;           // cell this lane LOADS rows for
  const int nH = half ? nB : nA;
  const int baseH = cH * CAP;
  const bf16x8* bqk = (const bf16x8*)(QKt + (size_t)(sA + half) * 1024);

  float num_acc[8], den_acc[8];
#pragma unroll
  for (int i = 0; i < 8; ++i) { num_acc[i] = 0.f; den_acc[i] = 0.f; }

  int ch = 0;
  do {
    const int s = c & 7;                     // token slot within this half
    const bool isOn = (ch == 0) & (s == 7);  // fixed on-grid slot
    const int jj = (ch == 0) ? s : 7 + (ch - 1) * 8 + s;
    const int sidx = sorted[baseH + (isOn ? 0 : min(jj, CAP - 1))];  // speculative
    const float* arow = isOn ? (ign ? fake : zc_on + (size_t)cH * E_)
                             : zc_off + (size_t)sidx * E_;
    arow += g * 8;

    bf16x8 af[4];
#pragma unroll
    for (int ks = 0; ks < 4; ++ks) {
      float4 a0 = *(const float4*)(arow + ks * 32);
      float4 a1 = *(const float4*)(arow + ks * 32 + 4);
      af[ks] = pack8(a0, a1);
    }

    // scores: S[t, n] = z_t . qk;  n<8 -> cell A head n, n>=8 -> cell B head n-8
    f32x4 aS = {0.f, 0.f, 0.f, 0.f};
#pragma unroll
    for (int ks = 0; ks < 4; ++ks)
      aS = __builtin_amdgcn_mfma_f32_16x16x32_bf16(af[ks], bqk[(ks * 4 + g) * 8 + (c & 7)], aS, 0, 0, 0);

    // only matching quadrants are real: row-half (hwr) == col-half (half)
    if (hwr == half) {
      float4 w4;
#pragma unroll
      for (int r = 0; r < 4; ++r) {
        const int sl = (g * 4 + r) & 7;
        const bool von = (ch == 0) & (sl == 7);
        const int tj = (ch == 0) ? sl : 7 + (ch - 1) * 8 + sl;
        ((float*)&w4)[r] = (von | (tj < nH)) ? __expf(aS[r]) : 0.f;
      }
      *(float4*)&wbuf[wave][c & 7][g * 4] = w4;   // one b128 write
    }
    // wave-internal ds_write -> ds_read ordering via compiler lgkmcnt

#pragma unroll 2
    for (int h = 0; h < 8; ++h) {
      const float4 wr4 = *(const float4*)&wbuf[wave][h][g * 4];  // one b128 read

      const int bo = g * 128 + c + h * 16;
      f32x4 aV = {0.f, 0.f, 0.f, 0.f};
#pragma unroll
      for (int ks = 0; ks < 4; ++ks)
        aV = __builtin_amdgcn_mfma_f32_16x16x32_bf16(af[ks], bv[bo + ks * 512], aV, 0, 0, 0);

      float sv = 0.f, sd;
      sv = fmaf(wr4.x, aV[0], sv);
      sv = fmaf(wr4.y, aV[1], sv);
      sv = fmaf(wr4.z, aV[2], sv);
      sv = fmaf(wr4.w, aV[3], sv);
      sd = wr4.x + wr4.y + wr4.z + wr4.w;
      num_acc[h] += sv;
      den_acc[h] += sd;
    }
  } while (++ch < 1 + (max(nA, nB) >> 3));

  // g0+g1 completes cell A (rows 0-7); g2+g3 completes cell B (rows 8-15)
#pragma unroll
  for (int i = 0; i < 8; ++i) {
    num_acc[i] += __shfl_xor(num_acc[i], 16, 64);
    den_acc[i] += __shfl_xor(den_acc[i], 16, 64);
  }
  const int hb = (g & 1) * 4;

  // ---- merged finalize: out = o @ Wo  (8 valid rows x 128 cols/block) ----
  const int lrow = wave * 2 + hwr;    // local cell row 0..7
#pragma unroll
  for (int b = 0; b < 4; ++b) {
    const int h = hb + b;
    obuf[lrow * 132 + h * 16 + c] = num_acc[h] / den_acc[h];
  }
  // preload this wave's Wo B-frags (global, L2-resident): 2 col-tiles
  bf16x8 wof[2][4];
#pragma unroll
  for (int nt = 0; nt < 2; ++nt)
#pragma unroll
    for (int ks = 0; ks < 4; ++ks)
      wof[nt][ks] = *(const bf16x8*)(Wo_sw +
          ((size_t)((ks * 4 + g) * 128 + wave * 32 + nt * 16 + c)) * 8);
  __syncthreads();

  const float* nrow = obuf + c * 132 + g * 8;
  f32x4 acc2[2] = {{0.f, 0.f, 0.f, 0.f}, {0.f, 0.f, 0.f, 0.f}};
#pragma unroll
  for (int ks = 0; ks < 4; ++ks) {
    float4 a0 = *(const float4*)(nrow + ks * 32);
    float4 a1 = *(const float4*)(nrow + ks * 32 + 4);
    const bf16x8 af = pack8(a0, a1);
#pragma unroll
    for (int nt = 0; nt < 2; ++nt)
      acc2[nt] = __builtin_amdgcn_mfma_f32_16x16x32_bf16(af, wof[nt][ks], acc2[nt], 0, 0, 0);
  }
  const int cell0 = blockIdx.x * 8;
  if (hwr == 0) {                     // rows 0..7 are the valid ones
#pragma unroll
    for (int nt = 0; nt < 2; ++nt)
#pragma unroll
      for (int r = 0; r < 4; ++r)
        out[(size_t)(cell0 + g * 4 + r) * E_ + wave * 32 + nt * 16 + c] = acc2[nt][r];
  }
}

// ------------------------------------------------------------------
extern "C" void kernel_launch(void* const* d_in, const int* in_sizes, int n_in,
                              void* d_out, int out_size, void* d_ws, size_t ws_size,
                              hipStream_t stream) {
  const float* xc_off  = (const float*)d_in[0];
  const float* zc_off  = (const float*)d_in[2];
  const float* zc_on   = (const float*)d_in[3];
  const float* latents = (const float*)d_in[4];
  const float* fake    = (const float*)d_in[5];
  const float* Wq      = (const float*)d_in[6];
  const float* Wk      = (const float*)d_in[7];
  const float* Wv      = (const float*)d_in[8];
  const float* Wo      = (const float*)d_in[9];
  const int*   ignore  = (const int*)d_in[10];

  float* out = (float*)d_out;

  // workspace layout (~12.7 MB)
  unsigned short* QKt = (unsigned short*)d_ws;               // S*1024 bf16 (8 MB)
  unsigned short* Wsw = QKt + (size_t)S_ * 1024;             // Wv,Wo bf16 (64 KB)
  int* cnt    = (int*)(Wsw + SWZ2);                          // NCELL (128 KB)
  int* sorted = cnt + NCELL;                                 // NCELL*CAP (4 MB)
  unsigned short* Ahi = (unsigned short*)(sorted + NCELL * CAP); // 256 KB
  unsigned short* Alo = Ahi + ASZ;                               // 256 KB
  unsigned short* Wv_sw = Wsw;
  unsigned short* Wo_sw = Wsw + 16384;

  // zero cnt AND sorted (adjacent) -- sorted must be 0 for speculative loads
  hipMemsetAsync(cnt, 0, NCELL * sizeof(int) * (1 + CAP), stream);
  setup_kernel<<<256, 1024, 0, stream>>>(Wq, Wk, Wv, Wo, xc_off,
                                         Wsw, Ahi, Alo, cnt, sorted);
  qkt_gemm<<<256, 512, 0, stream>>>(latents, Ahi, Alo, QKt);
  fused_cells<<<4096, 256, 0, stream>>>(zc_off, zc_on, fake, ignore,
                                        Wv_sw, Wo_sw, QKt, cnt, sorted, out);
}

// Round 6
// 196.590 us; speedup vs baseline: 1.2996x; 1.2996x over previous
//
#include <hip/hip_runtime.h>
#include <hip/hip_bf16.h>
#include <math.h>

namespace {
constexpr int B_  = 8;
constexpr int U_  = 16384;
constexpr int S_  = 4096;
constexpr int E_  = 128;
constexpr int NTOK  = B_ * U_;   // 131072
constexpr int NCELL = B_ * S_;   // 32768
constexpr int CAP = 32;          // max off-grid tokens per cell (Poisson λ~4.1)
constexpr int SWZ2 = 2 * 16384;  // Wv,Wo swizzle elements
constexpr int ASZ  = 128 * 1024; // A fold: 128 k x 1024 n entries
}

typedef __attribute__((ext_vector_type(8))) short bf16x8;
typedef __attribute__((ext_vector_type(4))) float f32x4;

__device__ inline unsigned short bf16rne(float x) {
  unsigned u = __float_as_uint(x);
  u = u + 0x7fffu + ((u >> 16) & 1u);
  return (unsigned short)(u >> 16);
}

__device__ inline float bf16tof(unsigned short h) {
  return __uint_as_float(((unsigned)h) << 16);
}

__device__ inline bf16x8 pack8(float4 a, float4 b) {
  union { __hip_bfloat162 h; unsigned int u; } q0, q1, q2, q3;
  q0.h = __float22bfloat162_rn(make_float2(a.x, a.y));
  q1.h = __float22bfloat162_rn(make_float2(a.z, a.w));
  q2.h = __float22bfloat162_rn(make_float2(b.x, b.y));
  q3.h = __float22bfloat162_rn(make_float2(b.z, b.w));
  union { unsigned int u[4]; bf16x8 v; } r;
  r.u[0] = q0.u; r.u[1] = q1.u; r.u[2] = q2.u; r.u[3] = q3.u;
  return r.v;
}

// ------------------------------------------------------------------
// L1 setup (256 blocks x 1024):
//  blocks 0..15 : A-fold (QKt = latents @ A with A = 0.25*Wq·Wk^T folded,
//                 hi+lo bf16 planes in B-frag layout).
//  blocks 16..255: swizzle Wv/Wo -> bf16 B-frag; bucketize + CAP-scatter.
// ------------------------------------------------------------------
__global__ __launch_bounds__(1024, 4) void setup_kernel(
    const float* __restrict__ Wq, const float* __restrict__ Wk,
    const float* __restrict__ Wv, const float* __restrict__ Wo,
    const float* __restrict__ xc_off,
    unsigned short* __restrict__ Wsw,
    unsigned short* __restrict__ Ahi, unsigned short* __restrict__ Alo,
    int* __restrict__ cnt, int* __restrict__ sorted) {
  const int tid = threadIdx.x;

  if (blockIdx.x < 16) {
    const int n = tid;                       // 0..1023
    const int eg = n >> 6, h = (n >> 3) & 7, el = n & 7;
    const int e = eg * 8 + el;
    const float* wk = Wk + (size_t)e * 128 + h * 16;
    float wkv[16];
#pragma unroll
    for (int j = 0; j < 16; j += 4) {
      float4 t = *(const float4*)(wk + j);
      wkv[j] = t.x; wkv[j + 1] = t.y; wkv[j + 2] = t.z; wkv[j + 3] = t.w;
    }
    union { unsigned short s[8]; uint4 v; } rh, rl;
#pragma unroll
    for (int r = 0; r < 8; ++r) {
      const int k = (blockIdx.x << 3) + r;
      const float* wq = Wq + (size_t)k * 128 + h * 16;
      float acc = 0.f;
#pragma unroll
      for (int j = 0; j < 16; j += 4) {
        float4 t = *(const float4*)(wq + j);
        acc = fmaf(t.x, wkv[j], acc);
        acc = fmaf(t.y, wkv[j + 1], acc);
        acc = fmaf(t.z, wkv[j + 2], acc);
        acc = fmaf(t.w, wkv[j + 3], acc);
      }
      acc *= 0.25f;
      const unsigned short hh = bf16rne(acc);
      rh.s[r] = hh;
      rl.s[r] = bf16rne(acc - bf16tof(hh));
    }
    const size_t fo = ((size_t)blockIdx.x * 1024 + n) * 8;
    *(uint4*)(Ahi + fo) = rh.v;
    *(uint4*)(Alo + fo) = rl.v;
  } else {
    const int base = (blockIdx.x - 16) * 1024 + tid;
    const int stride = 240 * 1024;
    for (int i = base; i < SWZ2 + NTOK; i += stride) {
      if (i < SWZ2) {
        const int w = i >> 14, e = i & 16383;
        const int k = e >> 7, n = e & 127;
        const float* src = (w == 0) ? Wv : Wo;
        Wsw[w * 16384 + (((k >> 3) * 128 + n) << 3) + (k & 7)] = bf16rne(src[e]);
      } else {
        const int tok = i - SWZ2;
        const int b = tok >> 14;
        // EXACT replication of reference fp32 bucketize math
        const float sp = 1.0f / 63.0f;
        const float half = sp * 0.5f;
        const float x0 = xc_off[(size_t)tok * 2 + 0];
        const float x1 = xc_off[(size_t)tok * 2 + 1];
        float n0 = floorf((x0 - 0.0f + half) / sp);
        float n1 = floorf((x1 - 0.0f + half) / sp);
        n0 = fminf(fmaxf(n0, 0.0f), 63.0f);
        n1 = fminf(fmaxf(n1, 0.0f), 63.0f);
        const int seg = b * S_ + (int)(n0 * 64.0f + n1);
        const int rank = atomicAdd(&cnt[seg], 1);
        if (rank < CAP) sorted[seg * CAP + rank] = tok;
      }
    }
  }
}

// ------------------------------------------------------------------
// L1b: QKt = latents (4096x128) @ (Ahi+Alo) (128x1024), bf16 out in the
// swizzled per-cell layout. 256 blocks x 512 thr. No LDS.
// ------------------------------------------------------------------
__global__ __launch_bounds__(512, 4) void qkt_gemm(
    const float* __restrict__ latents,
    const unsigned short* __restrict__ Ahi,
    const unsigned short* __restrict__ Alo,
    unsigned short* __restrict__ QKt) {
  const int tid = threadIdx.x;
  const int wave = tid >> 6, lane = tid & 63;
  const int c = lane & 15, g = lane >> 4;
  const int rb = blockIdx.x >> 1, cb = blockIdx.x & 1;
  const int wr = wave >> 2, wc = wave & 3;
  const int t0 = rb * 32 + wr * 16;
  const int n0 = cb * 512 + wc * 128;

  f32x4 acc[8];
#pragma unroll
  for (int i = 0; i < 8; ++i) acc[i] = {0.f, 0.f, 0.f, 0.f};

  const float* arow = latents + (size_t)(t0 + c) * E_ + g * 8;
#pragma unroll
  for (int ks = 0; ks < 4; ++ks) {
    float4 a0 = *(const float4*)(arow + ks * 32);
    float4 a1 = *(const float4*)(arow + ks * 32 + 4);
    bf16x8 af = pack8(a0, a1);
    const size_t kg = (size_t)(ks * 4 + g) * 1024;
#pragma unroll
    for (int nt = 0; nt < 8; ++nt) {
      const size_t fo = (kg + n0 + nt * 16 + c) * 8;
      acc[nt] = __builtin_amdgcn_mfma_f32_16x16x32_bf16(
          af, *(const bf16x8*)(Ahi + fo), acc[nt], 0, 0, 0);
      acc[nt] = __builtin_amdgcn_mfma_f32_16x16x32_bf16(
          af, *(const bf16x8*)(Alo + fo), acc[nt], 0, 0, 0);
    }
  }
#pragma unroll
  for (int nt = 0; nt < 8; ++nt)
#pragma unroll
    for (int r = 0; r < 4; ++r)
      QKt[(size_t)(t0 + g * 4 + r) * 1024 + n0 + nt * 16 + c] = bf16rne(acc[nt][r]);
}

// ------------------------------------------------------------------
// L2: fused per-cell kernel. 4096 blocks x 256 thr (4 waves = 4 slots =
// 8 cells per block). Same structure as prev round, but launch bounds
// RELAXED to (256,4): the (256,8) variant forced a 32-VGPR allocation
// and spilled to scratch (WRITE_SIZE 16->132 MB, 2.4x slower). 128-VGPR
// budget -> no spill; LDS 11.5 KB still allows 4-6 blocks/CU.
//  - NO Wv/Wo LDS staging: B-frags read from global (32 KB, L1/L2-hot).
//  - On-grid token at FIXED slot 7 of chunk 0 (softmax perm-invariant):
//    chunk-0 addresses cnt-independent; sorted pre-zeroed so speculative
//    loads are safe; cnt (one int2) joins only at the exp mask.
//  - do/while main loop; single epilogue barrier.
// ------------------------------------------------------------------
__global__ __launch_bounds__(256, 4) void fused_cells(
    const float* __restrict__ zc_off, const float* __restrict__ zc_on,
    const float* __restrict__ fake, const int* __restrict__ ignore_flag,
    const unsigned short* __restrict__ Wv_sw,
    const unsigned short* __restrict__ Wo_sw,
    const unsigned short* __restrict__ QKt, const int* __restrict__ cnt,
    const int* __restrict__ sorted, float* __restrict__ out) {
  __shared__ __align__(16) float wbuf[4][8][24];  // [wave][head][t 0..15 +pad]
  __shared__ __align__(16) float obuf[16 * 132];  // finalize tile (rows 8-15 zero)
  const int tid = threadIdx.x;
  // zero garbage rows 8..15 once (read by finalize MFMA, rows discarded)
  for (int i = 8 * 132 + tid; i < 16 * 132; i += 256) obuf[i] = 0.f;
  const int ign = *ignore_flag;

  const int wave = tid >> 6, lane = tid & 63;
  const int c = lane & 15, g = lane >> 4;
  const int half = c >> 3;   // col-half: 0 -> cell A heads, 1 -> cell B heads
  const int hwr  = g >> 1;   // row-half this lane's C rows belong to
  const bf16x8* bv = (const bf16x8*)Wv_sw;

  const int slot = blockIdx.x * 4 + wave;
  const int cA = slot * 2, cB = cA + 1;
  const int sA = cA & (S_ - 1);            // cA even => sA even, sB = sA+1
  const int2 cc = *(const int2*)(cnt + cA);  // one 8B load: {cnt[cA], cnt[cB]}
  const int nA = min(cc.x, CAP);
  const int nB = min(cc.y, CAP);
  const int cH = half ? cB : cA;           // cell this lane LOADS rows for
  const int nH = half ? nB : nA;
  const int baseH = cH * CAP;
  const bf16x8* bqk = (const bf16x8*)(QKt + (size_t)(sA + half) * 1024);

  float num_acc[8], den_acc[8];
#pragma unroll
  for (int i = 0; i < 8; ++i) { num_acc[i] = 0.f; den_acc[i] = 0.f; }

  int ch = 0;
  do {
    const int s = c & 7;                     // token slot within this half
    const bool isOn = (ch == 0) & (s == 7);  // fixed on-grid slot
    const int jj = (ch == 0) ? s : 7 + (ch - 1) * 8 + s;
    const int sidx = sorted[baseH + (isOn ? 0 : min(jj, CAP - 1))];  // speculative
    const float* arow = isOn ? (ign ? fake : zc_on + (size_t)cH * E_)
                             : zc_off + (size_t)sidx * E_;
    arow += g * 8;

    bf16x8 af[4];
#pragma unroll
    for (int ks = 0; ks < 4; ++ks) {
      float4 a0 = *(const float4*)(arow + ks * 32);
      float4 a1 = *(const float4*)(arow + ks * 32 + 4);
      af[ks] = pack8(a0, a1);
    }

    // scores: S[t, n] = z_t . qk;  n<8 -> cell A head n, n>=8 -> cell B head n-8
    f32x4 aS = {0.f, 0.f, 0.f, 0.f};
#pragma unroll
    for (int ks = 0; ks < 4; ++ks)
      aS = __builtin_amdgcn_mfma_f32_16x16x32_bf16(af[ks], bqk[(ks * 4 + g) * 8 + (c & 7)], aS, 0, 0, 0);

    // only matching quadrants are real: row-half (hwr) == col-half (half)
    if (hwr == half) {
      float4 w4;
#pragma unroll
      for (int r = 0; r < 4; ++r) {
        const int sl = (g * 4 + r) & 7;
        const bool von = (ch == 0) & (sl == 7);
        const int tj = (ch == 0) ? sl : 7 + (ch - 1) * 8 + sl;
        ((float*)&w4)[r] = (von | (tj < nH)) ? __expf(aS[r]) : 0.f;
      }
      *(float4*)&wbuf[wave][c & 7][g * 4] = w4;   // one b128 write
    }
    // wave-internal ds_write -> ds_read ordering via compiler lgkmcnt

#pragma unroll 2
    for (int h = 0; h < 8; ++h) {
      const float4 wr4 = *(const float4*)&wbuf[wave][h][g * 4];  // one b128 read

      const int bo = g * 128 + c + h * 16;
      f32x4 aV = {0.f, 0.f, 0.f, 0.f};
#pragma unroll
      for (int ks = 0; ks < 4; ++ks)
        aV = __builtin_amdgcn_mfma_f32_16x16x32_bf16(af[ks], bv[bo + ks * 512], aV, 0, 0, 0);

      float sv = 0.f, sd;
      sv = fmaf(wr4.x, aV[0], sv);
      sv = fmaf(wr4.y, aV[1], sv);
      sv = fmaf(wr4.z, aV[2], sv);
      sv = fmaf(wr4.w, aV[3], sv);
      sd = wr4.x + wr4.y + wr4.z + wr4.w;
      num_acc[h] += sv;
      den_acc[h] += sd;
    }
  } while (++ch < 1 + (max(nA, nB) >> 3));

  // g0+g1 completes cell A (rows 0-7); g2+g3 completes cell B (rows 8-15)
#pragma unroll
  for (int i = 0; i < 8; ++i) {
    num_acc[i] += __shfl_xor(num_acc[i], 16, 64);
    den_acc[i] += __shfl_xor(den_acc[i], 16, 64);
  }
  const int hb = (g & 1) * 4;

  // ---- merged finalize: out = o @ Wo  (8 valid rows x 128 cols/block) ----
  const int lrow = wave * 2 + hwr;    // local cell row 0..7
#pragma unroll
  for (int b = 0; b < 4; ++b) {
    const int h = hb + b;
    obuf[lrow * 132 + h * 16 + c] = num_acc[h] / den_acc[h];
  }
  // preload this wave's Wo B-frags (global, L2-resident): 2 col-tiles
  bf16x8 wof[2][4];
#pragma unroll
  for (int nt = 0; nt < 2; ++nt)
#pragma unroll
    for (int ks = 0; ks < 4; ++ks)
      wof[nt][ks] = *(const bf16x8*)(Wo_sw +
          ((size_t)((ks * 4 + g) * 128 + wave * 32 + nt * 16 + c)) * 8);
  __syncthreads();

  const float* nrow = obuf + c * 132 + g * 8;
  f32x4 acc2[2] = {{0.f, 0.f, 0.f, 0.f}, {0.f, 0.f, 0.f, 0.f}};
#pragma unroll
  for (int ks = 0; ks < 4; ++ks) {
    float4 a0 = *(const float4*)(nrow + ks * 32);
    float4 a1 = *(const float4*)(nrow + ks * 32 + 4);
    const bf16x8 af = pack8(a0, a1);
#pragma unroll
    for (int nt = 0; nt < 2; ++nt)
      acc2[nt] = __builtin_amdgcn_mfma_f32_16x16x32_bf16(af, wof[nt][ks], acc2[nt], 0, 0, 0);
  }
  const int cell0 = blockIdx.x * 8;
  if (hwr == 0) {                     // rows 0..7 are the valid ones
#pragma unroll
    for (int nt = 0; nt < 2; ++nt)
#pragma unroll
      for (int r = 0; r < 4; ++r)
        out[(size_t)(cell0 + g * 4 + r) * E_ + wave * 32 + nt * 16 + c] = acc2[nt][r];
  }
}

// ------------------------------------------------------------------
extern "C" void kernel_launch(void* const* d_in, const int* in_sizes, int n_in,
                              void* d_out, int out_size, void* d_ws, size_t ws_size,
                              hipStream_t stream) {
  const float* xc_off  = (const float*)d_in[0];
  const float* zc_off  = (const float*)d_in[2];
  const float* zc_on   = (const float*)d_in[3];
  const float* latents = (const float*)d_in[4];
  const float* fake    = (const float*)d_in[5];
  const float* Wq      = (const float*)d_in[6];
  const float* Wk      = (const float*)d_in[7];
  const float* Wv      = (const float*)d_in[8];
  const float* Wo      = (const float*)d_in[9];
  const int*   ignore  = (const int*)d_in[10];

  float* out = (float*)d_out;

  // workspace layout (~12.7 MB)
  unsigned short* QKt = (unsigned short*)d_ws;               // S*1024 bf16 (8 MB)
  unsigned short* Wsw = QKt + (size_t)S_ * 1024;             // Wv,Wo bf16 (64 KB)
  int* cnt    = (int*)(Wsw + SWZ2);                          // NCELL (128 KB)
  int* sorted = cnt + NCELL;                                 // NCELL*CAP (4 MB)
  unsigned short* Ahi = (unsigned short*)(sorted + NCELL * CAP); // 256 KB
  unsigned short* Alo = Ahi + ASZ;                               // 256 KB
  unsigned short* Wv_sw = Wsw;
  unsigned short* Wo_sw = Wsw + 16384;

  // zero cnt AND sorted (adjacent) -- sorted must be 0 for speculative loads
  hipMemsetAsync(cnt, 0, NCELL * sizeof(int) * (1 + CAP), stream);
  setup_kernel<<<256, 1024, 0, stream>>>(Wq, Wk, Wv, Wo, xc_off,
                                         Wsw, Ahi, Alo, cnt, sorted);
  qkt_gemm<<<256, 512, 0, stream>>>(latents, Ahi, Alo, QKt);
  fused_cells<<<4096, 256, 0, stream>>>(zc_off, zc_on, fake, ignore,
                                        Wv_sw, Wo_sw, QKt, cnt, sorted, out);
}

// Round 7
// 188.083 us; speedup vs baseline: 1.3584x; 1.0452x over previous
//
#include <hip/hip_runtime.h>
#include <hip/hip_bf16.h>
#include <math.h>

namespace {
constexpr int B_  = 8;
constexpr int U_  = 16384;
constexpr int S_  = 4096;
constexpr int E_  = 128;
constexpr int NTOK  = B_ * U_;   // 131072
constexpr int NCELL = B_ * S_;   // 32768
constexpr int CAP = 32;          // max off-grid tokens per cell (Poisson λ~4.1)
constexpr int SWZ2 = 2 * 16384;  // Wv,Wo swizzle elements
constexpr int ASZ  = 128 * 1024; // A fold: 128 k x 1024 n entries
}

typedef __attribute__((ext_vector_type(8))) short bf16x8;
typedef __attribute__((ext_vector_type(4))) float f32x4;

__device__ inline unsigned short bf16rne(float x) {
  unsigned u = __float_as_uint(x);
  u = u + 0x7fffu + ((u >> 16) & 1u);
  return (unsigned short)(u >> 16);
}

__device__ inline float bf16tof(unsigned short h) {
  return __uint_as_float(((unsigned)h) << 16);
}

__device__ inline bf16x8 pack8(float4 a, float4 b) {
  union { __hip_bfloat162 h; unsigned int u; } q0, q1, q2, q3;
  q0.h = __float22bfloat162_rn(make_float2(a.x, a.y));
  q1.h = __float22bfloat162_rn(make_float2(a.z, a.w));
  q2.h = __float22bfloat162_rn(make_float2(b.x, b.y));
  q3.h = __float22bfloat162_rn(make_float2(b.z, b.w));
  union { unsigned int u[4]; bf16x8 v; } r;
  r.u[0] = q0.u; r.u[1] = q1.u; r.u[2] = q2.u; r.u[3] = q3.u;
  return r.v;
}

// ------------------------------------------------------------------
// L1 setup (256 blocks x 1024):
//  blocks 0..15 : A-fold (QKt = latents @ A with A = 0.25*Wq·Wk^T folded,
//                 hi+lo bf16 planes in B-frag layout).
//  blocks 16..255: swizzle Wv/Wo -> bf16 B-frag; bucketize + CAP-scatter.
// ------------------------------------------------------------------
__global__ __launch_bounds__(1024, 4) void setup_kernel(
    const float* __restrict__ Wq, const float* __restrict__ Wk,
    const float* __restrict__ Wv, const float* __restrict__ Wo,
    const float* __restrict__ xc_off,
    unsigned short* __restrict__ Wsw,
    unsigned short* __restrict__ Ahi, unsigned short* __restrict__ Alo,
    int* __restrict__ cnt, int* __restrict__ sorted) {
  const int tid = threadIdx.x;

  if (blockIdx.x < 16) {
    const int n = tid;                       // 0..1023
    const int eg = n >> 6, h = (n >> 3) & 7, el = n & 7;
    const int e = eg * 8 + el;
    const float* wk = Wk + (size_t)e * 128 + h * 16;
    float wkv[16];
#pragma unroll
    for (int j = 0; j < 16; j += 4) {
      float4 t = *(const float4*)(wk + j);
      wkv[j] = t.x; wkv[j + 1] = t.y; wkv[j + 2] = t.z; wkv[j + 3] = t.w;
    }
    union { unsigned short s[8]; uint4 v; } rh, rl;
#pragma unroll
    for (int r = 0; r < 8; ++r) {
      const int k = (blockIdx.x << 3) + r;
      const float* wq = Wq + (size_t)k * 128 + h * 16;
      float acc = 0.f;
#pragma unroll
      for (int j = 0; j < 16; j += 4) {
        float4 t = *(const float4*)(wq + j);
        acc = fmaf(t.x, wkv[j], acc);
        acc = fmaf(t.y, wkv[j + 1], acc);
        acc = fmaf(t.z, wkv[j + 2], acc);
        acc = fmaf(t.w, wkv[j + 3], acc);
      }
      acc *= 0.25f;
      const unsigned short hh = bf16rne(acc);
      rh.s[r] = hh;
      rl.s[r] = bf16rne(acc - bf16tof(hh));
    }
    const size_t fo = ((size_t)blockIdx.x * 1024 + n) * 8;
    *(uint4*)(Ahi + fo) = rh.v;
    *(uint4*)(Alo + fo) = rl.v;
  } else {
    const int base = (blockIdx.x - 16) * 1024 + tid;
    const int stride = 240 * 1024;
    for (int i = base; i < SWZ2 + NTOK; i += stride) {
      if (i < SWZ2) {
        const int w = i >> 14, e = i & 16383;
        const int k = e >> 7, n = e & 127;
        const float* src = (w == 0) ? Wv : Wo;
        Wsw[w * 16384 + (((k >> 3) * 128 + n) << 3) + (k & 7)] = bf16rne(src[e]);
      } else {
        const int tok = i - SWZ2;
        const int b = tok >> 14;
        // EXACT replication of reference fp32 bucketize math
        const float sp = 1.0f / 63.0f;
        const float half = sp * 0.5f;
        const float x0 = xc_off[(size_t)tok * 2 + 0];
        const float x1 = xc_off[(size_t)tok * 2 + 1];
        float n0 = floorf((x0 - 0.0f + half) / sp);
        float n1 = floorf((x1 - 0.0f + half) / sp);
        n0 = fminf(fmaxf(n0, 0.0f), 63.0f);
        n1 = fminf(fmaxf(n1, 0.0f), 63.0f);
        const int seg = b * S_ + (int)(n0 * 64.0f + n1);
        const int rank = atomicAdd(&cnt[seg], 1);
        if (rank < CAP) sorted[seg * CAP + rank] = tok;
      }
    }
  }
}

// ------------------------------------------------------------------
// L1b: QKt = latents (4096x128) @ (Ahi+Alo) (128x1024), bf16 out in the
// swizzled per-cell layout. 256 blocks x 512 thr. No LDS.
// ------------------------------------------------------------------
__global__ __launch_bounds__(512, 4) void qkt_gemm(
    const float* __restrict__ latents,
    const unsigned short* __restrict__ Ahi,
    const unsigned short* __restrict__ Alo,
    unsigned short* __restrict__ QKt) {
  const int tid = threadIdx.x;
  const int wave = tid >> 6, lane = tid & 63;
  const int c = lane & 15, g = lane >> 4;
  const int rb = blockIdx.x >> 1, cb = blockIdx.x & 1;
  const int wr = wave >> 2, wc = wave & 3;
  const int t0 = rb * 32 + wr * 16;
  const int n0 = cb * 512 + wc * 128;

  f32x4 acc[8];
#pragma unroll
  for (int i = 0; i < 8; ++i) acc[i] = {0.f, 0.f, 0.f, 0.f};

  const float* arow = latents + (size_t)(t0 + c) * E_ + g * 8;
#pragma unroll
  for (int ks = 0; ks < 4; ++ks) {
    float4 a0 = *(const float4*)(arow + ks * 32);
    float4 a1 = *(const float4*)(arow + ks * 32 + 4);
    bf16x8 af = pack8(a0, a1);
    const size_t kg = (size_t)(ks * 4 + g) * 1024;
#pragma unroll
    for (int nt = 0; nt < 8; ++nt) {
      const size_t fo = (kg + n0 + nt * 16 + c) * 8;
      acc[nt] = __builtin_amdgcn_mfma_f32_16x16x32_bf16(
          af, *(const bf16x8*)(Ahi + fo), acc[nt], 0, 0, 0);
      acc[nt] = __builtin_amdgcn_mfma_f32_16x16x32_bf16(
          af, *(const bf16x8*)(Alo + fo), acc[nt], 0, 0, 0);
    }
  }
#pragma unroll
  for (int nt = 0; nt < 8; ++nt)
#pragma unroll
    for (int r = 0; r < 4; ++r)
      QKt[(size_t)(t0 + g * 4 + r) * 1024 + n0 + nt * 16 + c] = bf16rne(acc[nt][r]);
}

// ------------------------------------------------------------------
// L2: fused per-cell kernel. 2048 blocks x 512 thr (8 waves = 8 slots =
// 16 cells/block). R4 frame (Wv staged in LDS once per block -- the R5/R6
// global-Wv read was the regression: 32 KB re-read per wave-chunk from L2)
// + hoisted chain head:
//  - at kernel ENTRY (before Wv staging) issue: cnt int2, the 4 QKt
//    score-B-frags -> regs, and the FULL chunk-0 z-row gather -> 8 float4
//    regs. Chunk 0 is cnt-independent (on-grid token at fixed slot 7;
//    sorted[] pre-zeroed so speculative loads are safe), so all of this
//    HBM/L2 latency hides under the 32 KB staging + barrier.
//  - loop prefetches chunk ch+1's rows before chunk ch's V-loop.
//  - merged finalize epilogue (obuf aliases wv; two barriers).
// ------------------------------------------------------------------
__global__ __launch_bounds__(512, 4) void fused_cells(
    const float* __restrict__ zc_off, const float* __restrict__ zc_on,
    const float* __restrict__ fake, const int* __restrict__ ignore_flag,
    const unsigned short* __restrict__ Wv_sw,
    const unsigned short* __restrict__ Wo_sw,
    const unsigned short* __restrict__ QKt, const int* __restrict__ cnt,
    const int* __restrict__ sorted, float* __restrict__ out) {
  __shared__ __align__(16) unsigned short wv[16384];
  __shared__ __align__(16) float wbuf[8][8][24];  // [wave][head][t 0..15 +pad]
  const int tid = threadIdx.x;
  const int wave = tid >> 6, lane = tid & 63;
  const int c = lane & 15, g = lane >> 4;
  const int half = c >> 3;   // col-half: 0 -> cell A heads, 1 -> cell B heads
  const int hwr  = g >> 1;   // row-half this lane's C rows belong to

  const int slot = blockIdx.x * 8 + wave;
  const int cA = slot * 2, cB = cA + 1;
  const int sA = cA & (S_ - 1);              // cA even => sA even, sB = sA+1
  const int cH = half ? cB : cA;             // cell this lane LOADS rows for
  const int baseH = cH * CAP;

  // ---- hoisted chain head: issue all front-end loads NOW ----
  const int2 cc = *(const int2*)(cnt + cA);  // {cnt[cA], cnt[cB]}
  const int ign = *ignore_flag;

  bf16x8 bq[4];                              // score B-frags, register-resident
  {
    const bf16x8* bqk = (const bf16x8*)(QKt + (size_t)(sA + half) * 1024);
#pragma unroll
    for (int ks = 0; ks < 4; ++ks) bq[ks] = bqk[(ks * 4 + g) * 8 + (c & 7)];
  }

  float4 f4[8];                              // current chunk's z rows
  auto zload = [&](int ch) {
    const int s = c & 7;                     // token slot within this half
    const bool isOn = (ch == 0) & (s == 7);  // fixed on-grid slot
    const int jj = (ch == 0) ? s : 7 + (ch - 1) * 8 + s;
    const int sidx = sorted[baseH + (isOn ? 0 : min(jj, CAP - 1))];  // speculative
    const float* arow = isOn ? (ign ? fake : zc_on + (size_t)cH * E_)
                             : zc_off + (size_t)sidx * E_;
    arow += g * 8;
#pragma unroll
    for (int ks = 0; ks < 4; ++ks) {
      f4[2 * ks]     = *(const float4*)(arow + ks * 32);
      f4[2 * ks + 1] = *(const float4*)(arow + ks * 32 + 4);
    }
  };
  zload(0);                                  // chunk 0 is cnt-independent

  // ---- stage Wv into LDS (latency of loads above hides under this) ----
  {
    const uint4* sv = (const uint4*)Wv_sw;
    uint4* dv = (uint4*)wv;
#pragma unroll
    for (int i = 0; i < 4; ++i) dv[i * 512 + tid] = sv[i * 512 + tid];
  }
  __syncthreads();
  const bf16x8* bv = (const bf16x8*)wv;

  const int nA = min(cc.x, CAP);
  const int nB = min(cc.y, CAP);
  const int nH = half ? nB : nA;
  const int nch = 1 + (max(nA, nB) >> 3);

  float num_acc[8], den_acc[8];
#pragma unroll
  for (int i = 0; i < 8; ++i) { num_acc[i] = 0.f; den_acc[i] = 0.f; }

  int ch = 0;
  do {
    bf16x8 af[4];
#pragma unroll
    for (int ks = 0; ks < 4; ++ks) af[ks] = pack8(f4[2 * ks], f4[2 * ks + 1]);
    if (ch + 1 < nch) zload(ch + 1);         // prefetch next chunk (rare)

    // scores: S[t, n] = z_t . qk;  n<8 -> cell A head n, n>=8 -> cell B head n-8
    f32x4 aS = {0.f, 0.f, 0.f, 0.f};
#pragma unroll
    for (int ks = 0; ks < 4; ++ks)
      aS = __builtin_amdgcn_mfma_f32_16x16x32_bf16(af[ks], bq[ks], aS, 0, 0, 0);

    // only matching quadrants are real: row-half (hwr) == col-half (half)
    if (hwr == half) {
      float4 w4;
#pragma unroll
      for (int r = 0; r < 4; ++r) {
        const int sl = (g * 4 + r) & 7;
        const bool von = (ch == 0) & (sl == 7);
        const int tj = (ch == 0) ? sl : 7 + (ch - 1) * 8 + sl;
        ((float*)&w4)[r] = (von | (tj < nH)) ? __expf(aS[r]) : 0.f;
      }
      *(float4*)&wbuf[wave][c & 7][g * 4] = w4;   // one b128 write
    }
    // wave-internal ds_write -> ds_read ordering via compiler lgkmcnt

#pragma unroll 2
    for (int h = 0; h < 8; ++h) {
      const float4 wr4 = *(const float4*)&wbuf[wave][h][g * 4];  // one b128 read

      const int bo = g * 128 + c + h * 16;
      f32x4 aV = {0.f, 0.f, 0.f, 0.f};
#pragma unroll
      for (int ks = 0; ks < 4; ++ks)
        aV = __builtin_amdgcn_mfma_f32_16x16x32_bf16(af[ks], bv[bo + ks * 512], aV, 0, 0, 0);

      float sv = 0.f, sd;
      sv = fmaf(wr4.x, aV[0], sv);
      sv = fmaf(wr4.y, aV[1], sv);
      sv = fmaf(wr4.z, aV[2], sv);
      sv = fmaf(wr4.w, aV[3], sv);
      sd = wr4.x + wr4.y + wr4.z + wr4.w;
      num_acc[h] += sv;
      den_acc[h] += sd;
    }
  } while (++ch < nch);

  // g0+g1 completes cell A (rows 0-7); g2+g3 completes cell B (rows 8-15)
#pragma unroll
  for (int i = 0; i < 8; ++i) {
    num_acc[i] += __shfl_xor(num_acc[i], 16, 64);
    den_acc[i] += __shfl_xor(den_acc[i], 16, 64);
  }
  const int hb = (g & 1) * 4;

  // ---- merged finalize: out = o @ Wo ----
  // preload this wave's Wo B-frags (global, L2-resident) to hide latency
  // under the barrier wait
  bf16x8 wof[4];
#pragma unroll
  for (int ks = 0; ks < 4; ++ks)
    wof[ks] = *(const bf16x8*)(Wo_sw +
        ((size_t)((ks * 4 + g) * 128 + wave * 16 + c)) * 8);

  __syncthreads();                    // all waves done reading wv
  float* obuf = (float*)wv;           // [16][132] fp32 aliases wv (8448 B)
  const int lrow = wave * 2 + hwr;    // local cell row 0..15
#pragma unroll
  for (int b = 0; b < 4; ++b) {
    const int h = hb + b;
    obuf[lrow * 132 + h * 16 + c] = num_acc[h] / den_acc[h];
  }
  __syncthreads();

  const float* nrow = obuf + c * 132 + g * 8;
  f32x4 acc2 = {0.f, 0.f, 0.f, 0.f};
#pragma unroll
  for (int ks = 0; ks < 4; ++ks) {
    float4 a0 = *(const float4*)(nrow + ks * 32);
    float4 a1 = *(const float4*)(nrow + ks * 32 + 4);
    acc2 = __builtin_amdgcn_mfma_f32_16x16x32_bf16(pack8(a0, a1), wof[ks], acc2, 0, 0, 0);
  }
  const int cell0 = blockIdx.x * 16;
#pragma unroll
  for (int r = 0; r < 4; ++r)
    out[(size_t)(cell0 + g * 4 + r) * E_ + wave * 16 + c] = acc2[r];
}

// ------------------------------------------------------------------
extern "C" void kernel_launch(void* const* d_in, const int* in_sizes, int n_in,
                              void* d_out, int out_size, void* d_ws, size_t ws_size,
                              hipStream_t stream) {
  const float* xc_off  = (const float*)d_in[0];
  const float* zc_off  = (const float*)d_in[2];
  const float* zc_on   = (const float*)d_in[3];
  const float* latents = (const float*)d_in[4];
  const float* fake    = (const float*)d_in[5];
  const float* Wq      = (const float*)d_in[6];
  const float* Wk      = (const float*)d_in[7];
  const float* Wv      = (const float*)d_in[8];
  const float* Wo      = (const float*)d_in[9];
  const int*   ignore  = (const int*)d_in[10];

  float* out = (float*)d_out;

  // workspace layout (~12.7 MB)
  unsigned short* QKt = (unsigned short*)d_ws;               // S*1024 bf16 (8 MB)
  unsigned short* Wsw = QKt + (size_t)S_ * 1024;             // Wv,Wo bf16 (64 KB)
  int* cnt    = (int*)(Wsw + SWZ2);                          // NCELL (128 KB)
  int* sorted = cnt + NCELL;                                 // NCELL*CAP (4 MB)
  unsigned short* Ahi = (unsigned short*)(sorted + NCELL * CAP); // 256 KB
  unsigned short* Alo = Ahi + ASZ;                               // 256 KB
  unsigned short* Wv_sw = Wsw;
  unsigned short* Wo_sw = Wsw + 16384;

  // zero cnt AND sorted (adjacent) -- sorted must be 0 for speculative loads
  hipMemsetAsync(cnt, 0, NCELL * sizeof(int) * (1 + CAP), stream);
  setup_kernel<<<256, 1024, 0, stream>>>(Wq, Wk, Wv, Wo, xc_off,
                                         Wsw, Ahi, Alo, cnt, sorted);
  qkt_gemm<<<256, 512, 0, stream>>>(latents, Ahi, Alo, QKt);
  fused_cells<<<2048, 512, 0, stream>>>(zc_off, zc_on, fake, ignore,
                                        Wv_sw, Wo_sw, QKt, cnt, sorted, out);
}

// Round 8
// 180.818 us; speedup vs baseline: 1.4130x; 1.0402x over previous
//
#include <hip/hip_runtime.h>
#include <hip/hip_bf16.h>
#include <math.h>

namespace {
constexpr int B_  = 8;
constexpr int U_  = 16384;
constexpr int S_  = 4096;
constexpr int E_  = 128;
constexpr int NTOK  = B_ * U_;   // 131072
constexpr int NCELL = B_ * S_;   // 32768
constexpr int CAP = 32;          // max off-grid tokens per cell (Poisson λ~4.1)
constexpr int SWZ2 = 2 * 16384;  // Wv,Wo swizzle elements
constexpr int ASZ  = 128 * 1024; // A fold: 128 k x 1024 n entries
}

typedef __attribute__((ext_vector_type(8))) short bf16x8;
typedef __attribute__((ext_vector_type(4))) float f32x4;

__device__ inline unsigned short bf16rne(float x) {
  unsigned u = __float_as_uint(x);
  u = u + 0x7fffu + ((u >> 16) & 1u);
  return (unsigned short)(u >> 16);
}

__device__ inline float bf16tof(unsigned short h) {
  return __uint_as_float(((unsigned)h) << 16);
}

__device__ inline bf16x8 pack8(float4 a, float4 b) {
  union { __hip_bfloat162 h; unsigned int u; } q0, q1, q2, q3;
  q0.h = __float22bfloat162_rn(make_float2(a.x, a.y));
  q1.h = __float22bfloat162_rn(make_float2(a.z, a.w));
  q2.h = __float22bfloat162_rn(make_float2(b.x, b.y));
  q3.h = __float22bfloat162_rn(make_float2(b.z, b.w));
  union { unsigned int u[4]; bf16x8 v; } r;
  r.u[0] = q0.u; r.u[1] = q1.u; r.u[2] = q2.u; r.u[3] = q3.u;
  return r.v;
}

// ------------------------------------------------------------------
// L0 prep (48 blocks x 1024): replaces hipMemsetAsync + old setup A-fold.
//  blocks 0..15 : A-fold. A[k][n] = 0.25*sum_j Wq[k][h*16+j]*Wk[e][h*16+j],
//                 hi+lo bf16 planes in B-frag layout (verbatim from prior).
//  blocks 16..47: zero cnt[] (32768 ints, one per thread).
// ------------------------------------------------------------------
__global__ __launch_bounds__(1024, 4) void prep_kernel(
    const float* __restrict__ Wq, const float* __restrict__ Wk,
    unsigned short* __restrict__ Ahi, unsigned short* __restrict__ Alo,
    int* __restrict__ cnt) {
  const int tid = threadIdx.x;
  if (blockIdx.x < 16) {
    const int n = tid;                       // 0..1023
    const int eg = n >> 6, h = (n >> 3) & 7, el = n & 7;
    const int e = eg * 8 + el;
    const float* wk = Wk + (size_t)e * 128 + h * 16;
    float wkv[16];
#pragma unroll
    for (int j = 0; j < 16; j += 4) {
      float4 t = *(const float4*)(wk + j);
      wkv[j] = t.x; wkv[j + 1] = t.y; wkv[j + 2] = t.z; wkv[j + 3] = t.w;
    }
    union { unsigned short s[8]; uint4 v; } rh, rl;
#pragma unroll
    for (int r = 0; r < 8; ++r) {
      const int k = (blockIdx.x << 3) + r;
      const float* wq = Wq + (size_t)k * 128 + h * 16;
      float acc = 0.f;
#pragma unroll
      for (int j = 0; j < 16; j += 4) {
        float4 t = *(const float4*)(wq + j);
        acc = fmaf(t.x, wkv[j], acc);
        acc = fmaf(t.y, wkv[j + 1], acc);
        acc = fmaf(t.z, wkv[j + 2], acc);
        acc = fmaf(t.w, wkv[j + 3], acc);
      }
      acc *= 0.25f;
      const unsigned short hh = bf16rne(acc);
      rh.s[r] = hh;
      rl.s[r] = bf16rne(acc - bf16tof(hh));
    }
    const size_t fo = ((size_t)blockIdx.x * 1024 + n) * 8;
    *(uint4*)(Ahi + fo) = rh.v;
    *(uint4*)(Alo + fo) = rl.v;
  } else {
    cnt[(blockIdx.x - 16) * 1024 + tid] = 0;
  }
}

// ------------------------------------------------------------------
// L1 mid (256 blocks x 512): qkt GEMM and bucketize/swizzle CONCURRENT
// in one launch (they were serialized as two launches before).
//  blocks 0..127  : QKt = latents @ (Ahi+Alo), B-frag-RESIDENT redesign:
//                   each wave owns 32 cols, loads its 16 B-frags (hi+lo)
//                   into 64 VGPRs ONCE, loops 8 row-tiles reusing them
//                   (old qkt_gemm re-loaded every frag per MFMA: 128
//                   dependent L2 loads/lane, reuse 1x). Same MFMA order
//                   (ks asc, hi then lo) -> bit-identical output.
//                   Block: 8 waves x 32 cols = 256 cols, 128 rows.
//                   Grid: 32 row-groups x 4 col-groups.
//  blocks 128..255: swizzle Wv/Wo -> bf16 B-frag; bucketize + CAP-scatter
//                   (EXACT reference fp32 math, verbatim).
// ------------------------------------------------------------------
__global__ __launch_bounds__(512, 1) void mid_kernel(
    const float* __restrict__ latents,
    const unsigned short* __restrict__ Ahi,
    const unsigned short* __restrict__ Alo,
    unsigned short* __restrict__ QKt,
    const float* __restrict__ Wv, const float* __restrict__ Wo,
    const float* __restrict__ xc_off,
    unsigned short* __restrict__ Wsw,
    int* __restrict__ cnt, int* __restrict__ sorted) {
  const int tid = threadIdx.x;

  if (blockIdx.x < 128) {
    const int wave = tid >> 6, lane = tid & 63;
    const int c = lane & 15, g = lane >> 4;
    const int rb = blockIdx.x >> 2;          // 0..31: rows rb*128..+128
    const int cbg = blockIdx.x & 3;          // 0..3 : col quarter
    const int n0 = cbg * 256 + wave * 32;    // this wave's 32 cols

    // load this wave's B-frags once: [ks][nt] hi+lo
    bf16x8 bhi[4][2], blo[4][2];
#pragma unroll
    for (int ks = 0; ks < 4; ++ks) {
      const size_t kg = (size_t)(ks * 4 + g) * 1024;
#pragma unroll
      for (int nt = 0; nt < 2; ++nt) {
        const size_t fo = (kg + n0 + nt * 16 + c) * 8;
        bhi[ks][nt] = *(const bf16x8*)(Ahi + fo);
        blo[ks][nt] = *(const bf16x8*)(Alo + fo);
      }
    }

    for (int rt = 0; rt < 8; ++rt) {
      const int t0 = rb * 128 + rt * 16;
      f32x4 acc[2] = {{0.f, 0.f, 0.f, 0.f}, {0.f, 0.f, 0.f, 0.f}};
      const float* arow = latents + (size_t)(t0 + c) * E_ + g * 8;
#pragma unroll
      for (int ks = 0; ks < 4; ++ks) {
        float4 a0 = *(const float4*)(arow + ks * 32);
        float4 a1 = *(const float4*)(arow + ks * 32 + 4);
        const bf16x8 af = pack8(a0, a1);
#pragma unroll
        for (int nt = 0; nt < 2; ++nt) {
          acc[nt] = __builtin_amdgcn_mfma_f32_16x16x32_bf16(af, bhi[ks][nt], acc[nt], 0, 0, 0);
          acc[nt] = __builtin_amdgcn_mfma_f32_16x16x32_bf16(af, blo[ks][nt], acc[nt], 0, 0, 0);
        }
      }
#pragma unroll
      for (int nt = 0; nt < 2; ++nt)
#pragma unroll
        for (int r = 0; r < 4; ++r)
          QKt[(size_t)(t0 + g * 4 + r) * 1024 + n0 + nt * 16 + c] = bf16rne(acc[nt][r]);
    }
  } else {
    const int base = (blockIdx.x - 128) * 512 + tid;
    const int stride = 128 * 512;
    for (int i = base; i < SWZ2 + NTOK; i += stride) {
      if (i < SWZ2) {
        const int w = i >> 14, e = i & 16383;
        const int k = e >> 7, n = e & 127;
        const float* src = (w == 0) ? Wv : Wo;
        Wsw[w * 16384 + (((k >> 3) * 128 + n) << 3) + (k & 7)] = bf16rne(src[e]);
      } else {
        const int tok = i - SWZ2;
        const int b = tok >> 14;
        // EXACT replication of reference fp32 bucketize math
        const float sp = 1.0f / 63.0f;
        const float half = sp * 0.5f;
        const float x0 = xc_off[(size_t)tok * 2 + 0];
        const float x1 = xc_off[(size_t)tok * 2 + 1];
        float n0 = floorf((x0 - 0.0f + half) / sp);
        float n1 = floorf((x1 - 0.0f + half) / sp);
        n0 = fminf(fmaxf(n0, 0.0f), 63.0f);
        n1 = fminf(fmaxf(n1, 0.0f), 63.0f);
        const int seg = b * S_ + (int)(n0 * 64.0f + n1);
        const int rank = atomicAdd(&cnt[seg], 1);
        if (rank < CAP) sorted[seg * CAP + rank] = tok;
      }
    }
  }
}

// ------------------------------------------------------------------
// L2: fused per-cell kernel -- EXACT R4 structure (the best-measured
// variant: 50.5 us) + s_setprio(1) around the MFMA/exp/V cluster (T5:
// biases MFMA-phase waves over staging/load-phase waves on the CU
// scheduler; this kernel is in the latency regime where it pays).
// 2048 blocks x 512 thr, one slot (2 cells) per wave, Wv staged in LDS,
// transposed wbuf, merged finalize (obuf aliases wv).
// ------------------------------------------------------------------
__global__ __launch_bounds__(512, 4) void fused_cells(
    const float* __restrict__ zc_off, const float* __restrict__ zc_on,
    const float* __restrict__ fake, const int* __restrict__ ignore_flag,
    const unsigned short* __restrict__ Wv_sw,
    const unsigned short* __restrict__ Wo_sw,
    const unsigned short* __restrict__ QKt, const int* __restrict__ cnt,
    const int* __restrict__ sorted, float* __restrict__ out) {
  __shared__ __align__(16) unsigned short wv[16384];
  __shared__ __align__(16) float wbuf[8][8][24];  // [wave][head][t 0..15 +pad]
  const int tid = threadIdx.x;
  {
    const uint4* sv = (const uint4*)Wv_sw;
    uint4* dv = (uint4*)wv;
#pragma unroll
    for (int i = 0; i < 4; ++i) dv[i * 512 + tid] = sv[i * 512 + tid];
  }
  const int ign = *ignore_flag;
  __syncthreads();

  const int wave = tid >> 6, lane = tid & 63;
  const int c = lane & 15, g = lane >> 4;
  const int half = c >> 3;   // col-half: 0 -> cell A heads, 1 -> cell B heads
  const int hwr  = g >> 1;   // row-half this lane's C rows belong to
  const bf16x8* bv = (const bf16x8*)wv;

  const int slot = blockIdx.x * 8 + wave;
  const int cA = slot * 2, cB = cA + 1;
  const int sA = cA & (S_ - 1);            // cA even => sA even, sB = sA+1
  const int2 cc = *(const int2*)(cnt + cA);
  const int nA = min(cc.x, CAP);
  const int nB = min(cc.y, CAP);
  const int cH = half ? cB : cA;           // cell this lane LOADS rows for
  const int nH = half ? nB : nA;
  const int baseH = cH * CAP;
  const bf16x8* bqk = (const bf16x8*)(QKt + (size_t)(sA + half) * 1024);

  float num_acc[8], den_acc[8];
#pragma unroll
  for (int i = 0; i < 8; ++i) { num_acc[i] = 0.f; den_acc[i] = 0.f; }

  const int chunks = max((nA + 8) >> 3, (nB + 8) >> 3);

  for (int ch = 0; ch < chunks; ++ch) {
    const int jj = ch * 8 + (c & 7);       // token index within this lane's cell
    const float* arow;
    if (jj < nH)       arow = zc_off + (size_t)sorted[baseH + jj] * E_;
    else if (jj == nH) arow = ign ? fake : (zc_on + (size_t)cH * E_);
    else               arow = zc_on;       // pad: weight forced to 0
    arow += g * 8;

    bf16x8 af[4];
#pragma unroll
    for (int ks = 0; ks < 4; ++ks) {
      float4 a0 = *(const float4*)(arow + ks * 32);
      float4 a1 = *(const float4*)(arow + ks * 32 + 4);
      af[ks] = pack8(a0, a1);
    }

    __builtin_amdgcn_s_setprio(1);

    // scores: S[t, n] = z_t . qk;  n<8 -> cell A head n, n>=8 -> cell B head n-8
    f32x4 aS = {0.f, 0.f, 0.f, 0.f};
#pragma unroll
    for (int ks = 0; ks < 4; ++ks)
      aS = __builtin_amdgcn_mfma_f32_16x16x32_bf16(af[ks], bqk[(ks * 4 + g) * 8 + (c & 7)], aS, 0, 0, 0);

    // only matching quadrants are real: row-half (hwr) == col-half (half)
    if (hwr == half) {
      float4 w4;
#pragma unroll
      for (int r = 0; r < 4; ++r) {
        const int sl = (g * 4 + r) & 7;
        const int tj = ch * 8 + sl;
        ((float*)&w4)[r] = (tj <= nH) ? __expf(aS[r]) : 0.f;
      }
      *(float4*)&wbuf[wave][c & 7][g * 4] = w4;   // one b128 write
    }
    // wave-internal ds_write -> ds_read ordering via compiler lgkmcnt

#pragma unroll 2
    for (int h = 0; h < 8; ++h) {
      const float4 wr4 = *(const float4*)&wbuf[wave][h][g * 4];  // one b128 read

      const int bo = g * 128 + c + h * 16;
      f32x4 aV = {0.f, 0.f, 0.f, 0.f};
#pragma unroll
      for (int ks = 0; ks < 4; ++ks)
        aV = __builtin_amdgcn_mfma_f32_16x16x32_bf16(af[ks], bv[bo + ks * 512], aV, 0, 0, 0);

      float sv = 0.f, sd;
      sv = fmaf(wr4.x, aV[0], sv);
      sv = fmaf(wr4.y, aV[1], sv);
      sv = fmaf(wr4.z, aV[2], sv);
      sv = fmaf(wr4.w, aV[3], sv);
      sd = wr4.x + wr4.y + wr4.z + wr4.w;
      num_acc[h] += sv;
      den_acc[h] += sd;
    }

    __builtin_amdgcn_s_setprio(0);
  }

  // g0+g1 completes cell A (rows 0-7); g2+g3 completes cell B (rows 8-15)
#pragma unroll
  for (int i = 0; i < 8; ++i) {
    num_acc[i] += __shfl_xor(num_acc[i], 16, 64);
    den_acc[i] += __shfl_xor(den_acc[i], 16, 64);
  }
  const int hb = (g & 1) * 4;

  // ---- merged finalize: out = o @ Wo ----
  // preload this wave's Wo B-frags (global, L2-resident) to hide latency
  // under the barrier wait
  bf16x8 wof[4];
#pragma unroll
  for (int ks = 0; ks < 4; ++ks)
    wof[ks] = *(const bf16x8*)(Wo_sw +
        ((size_t)((ks * 4 + g) * 128 + wave * 16 + c)) * 8);

  __syncthreads();                    // all waves done reading wv
  float* obuf = (float*)wv;           // [16][132] fp32 aliases wv (8448 B)
  const int lrow = wave * 2 + hwr;    // local cell row 0..15
#pragma unroll
  for (int b = 0; b < 4; ++b) {
    const int h = hb + b;
    obuf[lrow * 132 + h * 16 + c] = num_acc[h] / den_acc[h];
  }
  __syncthreads();

  const float* nrow = obuf + c * 132 + g * 8;
  f32x4 acc2 = {0.f, 0.f, 0.f, 0.f};
#pragma unroll
  for (int ks = 0; ks < 4; ++ks) {
    float4 a0 = *(const float4*)(nrow + ks * 32);
    float4 a1 = *(const float4*)(nrow + ks * 32 + 4);
    acc2 = __builtin_amdgcn_mfma_f32_16x16x32_bf16(pack8(a0, a1), wof[ks], acc2, 0, 0, 0);
  }
  const int cell0 = blockIdx.x * 16;
#pragma unroll
  for (int r = 0; r < 4; ++r)
    out[(size_t)(cell0 + g * 4 + r) * E_ + wave * 16 + c] = acc2[r];
}

// ------------------------------------------------------------------
extern "C" void kernel_launch(void* const* d_in, const int* in_sizes, int n_in,
                              void* d_out, int out_size, void* d_ws, size_t ws_size,
                              hipStream_t stream) {
  const float* xc_off  = (const float*)d_in[0];
  const float* zc_off  = (const float*)d_in[2];
  const float* zc_on   = (const float*)d_in[3];
  const float* latents = (const float*)d_in[4];
  const float* fake    = (const float*)d_in[5];
  const float* Wq      = (const float*)d_in[6];
  const float* Wk      = (const float*)d_in[7];
  const float* Wv      = (const float*)d_in[8];
  const float* Wo      = (const float*)d_in[9];
  const int*   ignore  = (const int*)d_in[10];

  float* out = (float*)d_out;

  // workspace layout (~12.7 MB)
  unsigned short* QKt = (unsigned short*)d_ws;               // S*1024 bf16 (8 MB)
  unsigned short* Wsw = QKt + (size_t)S_ * 1024;             // Wv,Wo bf16 (64 KB)
  int* cnt    = (int*)(Wsw + SWZ2);                          // NCELL (128 KB)
  int* sorted = cnt + NCELL;                                 // NCELL*CAP (4 MB)
  unsigned short* Ahi = (unsigned short*)(sorted + NCELL * CAP); // 256 KB
  unsigned short* Alo = Ahi + ASZ;                               // 256 KB
  unsigned short* Wv_sw = Wsw;
  unsigned short* Wo_sw = Wsw + 16384;

  // 3 launches total: prep (A-fold + cnt zero), mid (qkt || bucketize), fused
  prep_kernel<<<48, 1024, 0, stream>>>(Wq, Wk, Ahi, Alo, cnt);
  mid_kernel<<<256, 512, 0, stream>>>(latents, Ahi, Alo, QKt,
                                      Wv, Wo, xc_off, Wsw, cnt, sorted);
  fused_cells<<<2048, 512, 0, stream>>>(zc_off, zc_on, fake, ignore,
                                        Wv_sw, Wo_sw, QKt, cnt, sorted, out);
}